// Round 1
// baseline (1084.871 us; speedup 1.0000x reference)
//
#include <hip/hip_runtime.h>
#include <hip/hip_bf16.h>
#include <math.h>

typedef unsigned short u16;
typedef __attribute__((ext_vector_type(8))) short short8;   // 8 bf16 (4 VGPRs)
typedef __attribute__((ext_vector_type(4))) float f32x4;    // MFMA C/D frag

// Problem constants: B=8, N=2048, D=DC=1024, K_centers=4, M = B*N = 16384.

__device__ __forceinline__ float bf2f(u16 b) {
  return __uint_as_float(((unsigned int)b) << 16);
}
__device__ __forceinline__ u16 f2bf(float f) {
  unsigned int u = __float_as_uint(f);
  u += 0x7FFFu + ((u >> 16) & 1u);   // round-to-nearest-even (finite inputs)
  return (u16)(u >> 16);
}
__device__ __forceinline__ float gelu_exact(float x) {
  return 0.5f * x * (1.0f + erff(x * 0.70710678118654752f));
}

// async 16B/lane global->LDS. LDS dest is wave-uniform base + lane*16.
__device__ __forceinline__ void cp16(const void* g, void* l) {
  __builtin_amdgcn_global_load_lds(
      (const __attribute__((address_space(1))) unsigned int*)g,
      (__attribute__((address_space(3))) unsigned int*)l, 16, 0, 0);
}

// ---------------------------------------------------------------------------
// GEMM: C[M,Nout] = A[M,K](bf16) @ Wt[Nout,K]^T(bf16)  (Wt stored row-major [Nout,K])
// 128x128 tile, BK=64, 4 waves (2x2), each wave 64x64 via 4x4 of 16x16x32 MFMA.
// LDS quad-XOR swizzle: LDS slot (row, q) holds global quad (q ^ (row&7)) so the
// column-strided ds_read_b128 fragment reads are <=2-way bank aliased (free).
// GATHER=true implements the jnp.roll fusion for fr1: logical A[m, k] =
//   x[b, (n - shift[k>>10]) & 2047, k & 1023], shifts = {1,-1,0,2,-2,4,-4}.
// MODE: 0 = gelu->bf16      (out0 bf16, ldo0)
//       1 = bias only       -> out1 f32 (x_ring, ld 1024) + out0 bf16 (fus2, ldo0)
//       2 = bias only       -> out0 bf16
//       3 = sigmoid         -> out0 f32 (gate)
//       4 = final: out0 f32 = gate*(c+bias) + (1-gate)*xring
// ---------------------------------------------------------------------------
template <int MODE, bool GATHER>
__global__ __launch_bounds__(256) void gemm128(
    const u16* __restrict__ A, int lda, const u16* __restrict__ Wt, int K,
    const float* __restrict__ bias, void* __restrict__ out0, int ldo0,
    float* __restrict__ out1, const float* __restrict__ gate,
    const float* __restrict__ xring) {
  __shared__ __align__(16) u16 As[128 * 64];
  __shared__ __align__(16) u16 Bs[128 * 64];

  const int tid = threadIdx.x;
  const int lane = tid & 63;
  const int wave = tid >> 6;     // 0..3
  const int wm = wave >> 1;      // wave row in 2x2
  const int wn = wave & 1;       // wave col
  const int m0 = blockIdx.y * 128;
  const int n0 = blockIdx.x * 128;

  const int srow = lane >> 3;    // 0..7: row within an 8-row staging chunk
  const int sq = lane & 7;       // quad (16B) within a 128B row
  const int sqs = sq ^ srow;     // swizzled global quad

  f32x4 acc[4][4];
#pragma unroll
  for (int i = 0; i < 4; i++)
#pragma unroll
    for (int j = 0; j < 4; j++) acc[i][j] = (f32x4){0.f, 0.f, 0.f, 0.f};

  for (int k0 = 0; k0 < K; k0 += 64) {
    // ---- stage A tile (16 KB): As[row][q] <- A[m0+row][k0 + (q^(row&7))*8 ..]
#pragma unroll
    for (int i = 0; i < 4; i++) {
      const int rloc = wave * 32 + i * 8 + srow;   // 0..127
      long gofs;
      if (GATHER) {
        const int seg = k0 >> 10;                  // uniform per iteration
        int shift;
        switch (seg) {
          case 0: shift = 1; break;
          case 1: shift = -1; break;
          case 2: shift = 0; break;
          case 3: shift = 2; break;
          case 4: shift = -2; break;
          case 5: shift = 4; break;
          default: shift = -4; break;
        }
        const int m = m0 + rloc;
        const int b = m >> 11;                     // N = 2048 = 2^11
        const int nsrc = ((m & 2047) - shift) & 2047;
        gofs = (long)((b << 11) | nsrc) * 1024 + (k0 & 1023) + sqs * 8;
      } else {
        gofs = (long)(m0 + rloc) * lda + k0 + sqs * 8;
      }
      cp16(A + gofs, &As[(wave * 32 + i * 8) * 64]);
    }
    // ---- stage B tile: Bs[nrow][q] <- Wt[n0+nrow][k0 + (q^(nrow&7))*8 ..]
#pragma unroll
    for (int i = 0; i < 4; i++) {
      const int rloc = wave * 32 + i * 8 + srow;
      const long gofs = (long)(n0 + rloc) * K + k0 + sqs * 8;
      cp16(Wt + gofs, &Bs[(wave * 32 + i * 8) * 64]);
    }
    __syncthreads();   // compiler emits vmcnt(0) drain before s_barrier

    const int q4 = lane >> 4;     // 0..3
    const int r16 = lane & 15;
#pragma unroll
    for (int kk = 0; kk < 2; kk++) {
      short8 af[4], bf[4];
#pragma unroll
      for (int mi = 0; mi < 4; mi++) {
        const int row = wm * 64 + mi * 16 + r16;
        const int q = (kk * 4 + q4) ^ (row & 7);
        af[mi] = *(const short8*)&As[row * 64 + q * 8];
      }
#pragma unroll
      for (int ni = 0; ni < 4; ni++) {
        const int row = wn * 64 + ni * 16 + r16;
        const int q = (kk * 4 + q4) ^ (row & 7);
        bf[ni] = *(const short8*)&Bs[row * 64 + q * 8];
      }
#pragma unroll
      for (int mi = 0; mi < 4; mi++)
#pragma unroll
        for (int ni = 0; ni < 4; ni++)
          acc[mi][ni] = __builtin_amdgcn_mfma_f32_16x16x32_bf16(
              af[mi], bf[ni], acc[mi][ni], 0, 0, 0);
    }
    __syncthreads();
  }

  // epilogue: C/D layout col = lane&15, row = (lane>>4)*4 + reg
  const int ccol = lane & 15;
  const int crow = (lane >> 4) * 4;
#pragma unroll
  for (int mi = 0; mi < 4; mi++) {
#pragma unroll
    for (int ni = 0; ni < 4; ni++) {
#pragma unroll
      for (int r = 0; r < 4; r++) {
        const int m = m0 + wm * 64 + mi * 16 + crow + r;
        const int n = n0 + wn * 64 + ni * 16 + ccol;
        const float v = acc[mi][ni][r] + bias[n];
        if (MODE == 0) {
          ((u16*)out0)[(long)m * ldo0 + n] = f2bf(gelu_exact(v));
        } else if (MODE == 1) {
          out1[(long)m * 1024 + n] = v;
          ((u16*)out0)[(long)m * ldo0 + n] = f2bf(v);
        } else if (MODE == 2) {
          ((u16*)out0)[(long)m * ldo0 + n] = f2bf(v);
        } else if (MODE == 3) {
          ((float*)out0)[(long)m * ldo0 + n] = 1.0f / (1.0f + expf(-v));
        } else {  // MODE 4
          const float g = gate[(long)m * 1024 + n];
          const float xr = xring[(long)m * 1024 + n];
          ((float*)out0)[(long)m * ldo0 + n] = g * v + (1.0f - g) * xr;
        }
      }
    }
  }
}

// fp32 -> bf16 cast, 4 elems/thread
__global__ __launch_bounds__(256) void cast_bf16(const float* __restrict__ in,
                                                 u16* __restrict__ out, int n4) {
  const long i = (long)blockIdx.x * 256 + threadIdx.x;
  if (i < n4) {
    const float4 v = ((const float4*)in)[i];
    ushort4 o;
    o.x = f2bf(v.x); o.y = f2bf(v.y); o.z = f2bf(v.z); o.w = f2bf(v.w);
    ((ushort4*)out)[i] = o;
  }
}

// W[K,N] fp32 -> Wt[N,K] bf16, 32x32 LDS tile transpose
__global__ __launch_bounds__(256) void transp_bf16(const float* __restrict__ in,
                                                   u16* __restrict__ out, int K,
                                                   int N) {
  __shared__ float tile[32][33];
  const int tx = threadIdx.x & 31;
  const int ty = threadIdx.x >> 5;  // 0..7
  const long r0 = (long)blockIdx.y * 32;
  const long c0 = (long)blockIdx.x * 32;
#pragma unroll
  for (int r = 0; r < 4; r++)
    tile[ty + r * 8][tx] = in[(r0 + ty + r * 8) * N + c0 + tx];
  __syncthreads();
#pragma unroll
  for (int r = 0; r < 4; r++)
    out[(c0 + ty + r * 8) * K + r0 + tx] = f2bf(tile[tx][ty + r * 8]);
}

// K=4 cluster: logits = token_proj . centers_k, softmax, weighted = w @ centers
// one wave per token; writes bf16 into fus2[:, 1024:2048]
__global__ __launch_bounds__(256) void centers_kernel(
    const u16* __restrict__ tp, const float* __restrict__ centers,
    u16* __restrict__ fus2) {
  const int lane = threadIdx.x & 63;
  const int wave = threadIdx.x >> 6;
  const long t = (long)blockIdx.x * 4 + wave;
  const u16* row = tp + t * 1024;
  float d0 = 0.f, d1 = 0.f, d2 = 0.f, d3 = 0.f;
#pragma unroll
  for (int j = 0; j < 2; j++) {
    const int dbase = j * 512 + lane * 8;
    const short8 v = *(const short8*)(row + dbase);
#pragma unroll
    for (int e = 0; e < 8; e++) {
      const float x = bf2f((u16)v[e]);
      const int d = dbase + e;
      d0 += x * centers[d];
      d1 += x * centers[1024 + d];
      d2 += x * centers[2048 + d];
      d3 += x * centers[3072 + d];
    }
  }
#pragma unroll
  for (int off = 32; off > 0; off >>= 1) {
    d0 += __shfl_xor(d0, off);
    d1 += __shfl_xor(d1, off);
    d2 += __shfl_xor(d2, off);
    d3 += __shfl_xor(d3, off);
  }
  const float mx = fmaxf(fmaxf(d0, d1), fmaxf(d2, d3));
  float e0 = expf(d0 - mx), e1 = expf(d1 - mx), e2 = expf(d2 - mx),
        e3 = expf(d3 - mx);
  const float inv = 1.0f / (e0 + e1 + e2 + e3);
  e0 *= inv; e1 *= inv; e2 *= inv; e3 *= inv;
#pragma unroll
  for (int j = 0; j < 2; j++) {
    const int dbase = j * 512 + lane * 8;
    short8 o;
#pragma unroll
    for (int e = 0; e < 8; e++) {
      const int d = dbase + e;
      const float wv = e0 * centers[d] + e1 * centers[1024 + d] +
                       e2 * centers[2048 + d] + e3 * centers[3072 + d];
      o[e] = (short)f2bf(wv);
    }
    *(short8*)(fus2 + t * 2048 + 1024 + dbase) = o;
  }
}

extern "C" void kernel_launch(void* const* d_in, const int* in_sizes, int n_in,
                              void* d_out, int out_size, void* d_ws,
                              size_t ws_size, hipStream_t stream) {
  const float* queries = (const float*)d_in[0];
  const float* fr_w1 = (const float*)d_in[1];
  const float* fr_b1 = (const float*)d_in[2];
  const float* fr_w2 = (const float*)d_in[3];
  const float* fr_b2 = (const float*)d_in[4];
  const float* tc_w1 = (const float*)d_in[5];
  const float* tc_b1 = (const float*)d_in[6];
  const float* tc_w2 = (const float*)d_in[7];
  const float* tc_b2 = (const float*)d_in[8];
  const float* centers = (const float*)d_in[9];
  const float* fc_w1 = (const float*)d_in[10];
  const float* fc_b1 = (const float*)d_in[11];
  const float* fc_w2 = (const float*)d_in[12];
  const float* fc_b2 = (const float*)d_in[13];
  const float* g_w = (const float*)d_in[14];
  const float* g_b = (const float*)d_in[15];

  char* ws = (char*)d_ws;
  u16* Wt1 = (u16*)ws; ws += (size_t)7168 * 1024 * 2;   // fr_w1^T
  u16* Wt2 = (u16*)ws; ws += (size_t)1024 * 1024 * 2;   // fr_w2^T
  u16* Wt3 = (u16*)ws; ws += (size_t)1024 * 1024 * 2;   // tc_w1^T
  u16* Wt4 = (u16*)ws; ws += (size_t)1024 * 1024 * 2;   // tc_w2^T
  u16* Wt5 = (u16*)ws; ws += (size_t)1024 * 2048 * 2;   // fc_w1^T
  u16* Wt6 = (u16*)ws; ws += (size_t)1024 * 1024 * 2;   // fc_w2^T
  u16* Wt7 = (u16*)ws; ws += (size_t)1024 * 2048 * 2;   // g_w^T
  u16* Xb = (u16*)ws;  ws += (size_t)16384 * 1024 * 2;  // bf16 queries; reused as h2, fch
  u16* h1 = (u16*)ws;  ws += (size_t)16384 * 1024 * 2;  // ring hidden; reused as token_proj
  float* xring = (float*)ws; ws += (size_t)16384 * 1024 * 4;  // x_ring fp32
  u16* fus2 = (u16*)ws; ws += (size_t)16384 * 2048 * 2; // [x_ring_bf16 | weighted]
  float* gate = (float*)d_out;  // gate fp32 lives in d_out (read-then-overwrite)
  float* out = (float*)d_out;

  // --- precision conversions (per-call; harness restores inputs each launch) ---
  cast_bf16<<<16384, 256, 0, stream>>>(queries, Xb, 16384 * 1024 / 4);
  transp_bf16<<<dim3(32, 224), 256, 0, stream>>>(fr_w1, Wt1, 7168, 1024);
  transp_bf16<<<dim3(32, 32), 256, 0, stream>>>(fr_w2, Wt2, 1024, 1024);
  transp_bf16<<<dim3(32, 32), 256, 0, stream>>>(tc_w1, Wt3, 1024, 1024);
  transp_bf16<<<dim3(32, 32), 256, 0, stream>>>(tc_w2, Wt4, 1024, 1024);
  transp_bf16<<<dim3(32, 64), 256, 0, stream>>>(fc_w1, Wt5, 2048, 1024);
  transp_bf16<<<dim3(32, 32), 256, 0, stream>>>(fc_w2, Wt6, 1024, 1024);
  transp_bf16<<<dim3(32, 64), 256, 0, stream>>>(g_w, Wt7, 2048, 1024);

  const dim3 grid(8, 128);  // Nout/128 x M/128
  // fr1: gelu(fusion @ fr_w1 + b1) with fused roll-gather -> h1
  gemm128<0, true><<<grid, 256, 0, stream>>>(Xb, 0, Wt1, 7168, fr_b1, h1, 1024,
                                             nullptr, nullptr, nullptr);
  // fr2: x_ring = h1 @ fr_w2 + b2 -> xring(f32) + fus2[:, :1024](bf16)
  gemm128<1, false><<<grid, 256, 0, stream>>>(h1, 1024, Wt2, 1024, fr_b2, fus2,
                                              2048, xring, nullptr, nullptr);
  // tc1: gelu(x_ring @ tc_w1 + b1) -> h2 (Xb buffer)
  gemm128<0, false><<<grid, 256, 0, stream>>>(fus2, 2048, Wt3, 1024, tc_b1, Xb,
                                              1024, nullptr, nullptr, nullptr);
  // tc2: token_proj = h2 @ tc_w2 + b2 -> h1 buffer
  gemm128<2, false><<<grid, 256, 0, stream>>>(Xb, 1024, Wt4, 1024, tc_b2, h1,
                                              1024, nullptr, nullptr, nullptr);
  // softmax over 4 centers + weighted sum -> fus2[:, 1024:2048]
  centers_kernel<<<4096, 256, 0, stream>>>(h1, centers, fus2);
  // gate = sigmoid(fus2 @ g_w + g_b) -> d_out (f32 scratch)
  gemm128<3, false><<<grid, 256, 0, stream>>>(fus2, 2048, Wt7, 2048, g_b, gate,
                                              1024, nullptr, nullptr, nullptr);
  // fc1: gelu(fus2 @ fc_w1 + b1) -> fch (Xb buffer)
  gemm128<0, false><<<grid, 256, 0, stream>>>(fus2, 2048, Wt5, 2048, fc_b1, Xb,
                                              1024, nullptr, nullptr, nullptr);
  // fc2 + final mix: out = gate*(fch @ fc_w2 + b2) + (1-gate)*x_ring
  gemm128<4, false><<<grid, 256, 0, stream>>>(Xb, 1024, Wt6, 1024, fc_b2, out,
                                              1024, nullptr, gate, xring);
}

// Round 2
// 910.122 us; speedup vs baseline: 1.1920x; 1.1920x over previous
//
#include <hip/hip_runtime.h>
#include <hip/hip_bf16.h>
#include <math.h>

typedef unsigned short u16;
typedef __attribute__((ext_vector_type(8))) short short8;   // 8 bf16 (4 VGPRs)
typedef __attribute__((ext_vector_type(4))) float f32x4;    // MFMA C/D frag

// Problem constants: B=8, N=2048, D=DC=1024, K_centers=4, M = B*N = 16384.

__device__ __forceinline__ float bf2f(u16 b) {
  return __uint_as_float(((unsigned int)b) << 16);
}
__device__ __forceinline__ u16 f2bf(float f) {
  unsigned int u = __float_as_uint(f);
  u += 0x7FFFu + ((u >> 16) & 1u);   // round-to-nearest-even (finite inputs)
  return (u16)(u >> 16);
}
__device__ __forceinline__ float gelu_exact(float x) {
  return 0.5f * x * (1.0f + erff(x * 0.70710678118654752f));
}

// async 16B/lane global->LDS. LDS dest is wave-uniform base + lane*16.
__device__ __forceinline__ void cp16(const void* g, void* l) {
  __builtin_amdgcn_global_load_lds(
      (const __attribute__((address_space(1))) unsigned int*)g,
      (__attribute__((address_space(3))) unsigned int*)l, 16, 0, 0);
}

// ---------------------------------------------------------------------------
// GEMM: C[M,Nout] = A[M,K](bf16) @ Wt[Nout,K]^T(bf16)  (Wt row-major [Nout,K])
// 128x128 tile, BK=64, 4 waves (2x2), each wave 64x64 via 4x4 of 16x16x32 MFMA.
// LDS quad-XOR swizzle keeps fragment ds_read_b128 <=2-way bank aliased (free).
// XCD swizzle: linear%8 -> XCD (HW round-robin); within an XCD, bx varies
// fastest so the 8..16 blocks sharing an A m-tile are time-adjacent on the
// same XCD's 4 MB L2, and each XCD covers a compact 1/8 m-range (A fetched
// ~once from HBM instead of once per XCD).
// GATHER=true implements the jnp.roll fusion for fr1: logical A[m, k] =
//   x[b, (n - shift[k>>10]) & 2047, k & 1023], shifts = {1,-1,0,2,-2,4,-4}.
// MODE: 0 = gelu->bf16 out0 (ldo0)
//       1 = bias only -> out1 f32 (x_ring, ld 1024) + out0 bf16 (fus2, ldo0)
//       2 = bias only -> out0 bf16
//       4 = final: out0 f32 = gate*(c+bias) + (1-gate)*xring
//       5 = merged gate|fc1 (Nout=2048): n<1024 -> sigmoid f32 to out0[.,n];
//           n>=1024 -> gelu bf16 to out1[., n-1024]; bias2 for upper half
// ---------------------------------------------------------------------------
template <int MODE, bool GATHER>
__global__ __launch_bounds__(256) void gemm128(
    const u16* __restrict__ A, int lda, const u16* __restrict__ Wt, int K,
    const float* __restrict__ bias, const float* __restrict__ bias2,
    void* __restrict__ out0, int ldo0, void* __restrict__ out1,
    const float* __restrict__ gate, const float* __restrict__ xring) {
  __shared__ __align__(16) u16 As[128 * 64];
  __shared__ __align__(16) u16 Bs[128 * 64];

  const int tid = threadIdx.x;
  const int lane = tid & 63;
  const int wave = tid >> 6;     // 0..3
  const int wm = wave >> 1;      // wave row in 2x2
  const int wn = wave & 1;       // wave col

  // ---- XCD-aware block swizzle (gridDim.y divisible by 8) ----
  const unsigned linear = blockIdx.y * gridDim.x + blockIdx.x;
  const unsigned xcd = linear & 7u;
  const unsigned pos = linear >> 3;
  const unsigned bx = pos % gridDim.x;
  const unsigned by = xcd * (gridDim.y >> 3) + pos / gridDim.x;
  const int m0 = by * 128;
  const int n0 = bx * 128;

  const int srow = lane >> 3;    // 0..7: row within an 8-row staging chunk
  const int sq = lane & 7;       // quad (16B) within a 128B row
  const int sqs = sq ^ srow;     // swizzled global quad

  f32x4 acc[4][4];
#pragma unroll
  for (int i = 0; i < 4; i++)
#pragma unroll
    for (int j = 0; j < 4; j++) acc[i][j] = (f32x4){0.f, 0.f, 0.f, 0.f};

  for (int k0 = 0; k0 < K; k0 += 64) {
    // ---- stage A tile (16 KB): As[row][q] <- A[m0+row][k0 + (q^(row&7))*8 ..]
#pragma unroll
    for (int i = 0; i < 4; i++) {
      const int rloc = wave * 32 + i * 8 + srow;   // 0..127
      long gofs;
      if (GATHER) {
        const int seg = k0 >> 10;                  // uniform per iteration
        int shift;
        switch (seg) {
          case 0: shift = 1; break;
          case 1: shift = -1; break;
          case 2: shift = 0; break;
          case 3: shift = 2; break;
          case 4: shift = -2; break;
          case 5: shift = 4; break;
          default: shift = -4; break;
        }
        const int m = m0 + rloc;
        const int b = m >> 11;                     // N = 2048 = 2^11
        const int nsrc = ((m & 2047) - shift) & 2047;
        gofs = (long)((b << 11) | nsrc) * 1024 + (k0 & 1023) + sqs * 8;
      } else {
        gofs = (long)(m0 + rloc) * lda + k0 + sqs * 8;
      }
      cp16(A + gofs, &As[(wave * 32 + i * 8) * 64]);
    }
    // ---- stage B tile: Bs[nrow][q] <- Wt[n0+nrow][k0 + (q^(nrow&7))*8 ..]
#pragma unroll
    for (int i = 0; i < 4; i++) {
      const int rloc = wave * 32 + i * 8 + srow;
      const long gofs = (long)(n0 + rloc) * K + k0 + sqs * 8;
      cp16(Wt + gofs, &Bs[(wave * 32 + i * 8) * 64]);
    }
    __syncthreads();

    const int q4 = lane >> 4;     // 0..3
    const int r16 = lane & 15;
#pragma unroll
    for (int kk = 0; kk < 2; kk++) {
      short8 af[4], bf[4];
#pragma unroll
      for (int mi = 0; mi < 4; mi++) {
        const int row = wm * 64 + mi * 16 + r16;
        const int q = (kk * 4 + q4) ^ (row & 7);
        af[mi] = *(const short8*)&As[row * 64 + q * 8];
      }
#pragma unroll
      for (int ni = 0; ni < 4; ni++) {
        const int row = wn * 64 + ni * 16 + r16;
        const int q = (kk * 4 + q4) ^ (row & 7);
        bf[ni] = *(const short8*)&Bs[row * 64 + q * 8];
      }
#pragma unroll
      for (int mi = 0; mi < 4; mi++)
#pragma unroll
        for (int ni = 0; ni < 4; ni++)
          acc[mi][ni] = __builtin_amdgcn_mfma_f32_16x16x32_bf16(
              af[mi], bf[ni], acc[mi][ni], 0, 0, 0);
    }
    __syncthreads();
  }

  // epilogue: C/D layout col = lane&15, row = (lane>>4)*4 + reg
  const int ccol = lane & 15;
  const int crow = (lane >> 4) * 4;
#pragma unroll
  for (int mi = 0; mi < 4; mi++) {
#pragma unroll
    for (int ni = 0; ni < 4; ni++) {
#pragma unroll
      for (int r = 0; r < 4; r++) {
        const int m = m0 + wm * 64 + mi * 16 + crow + r;
        const int n = n0 + wn * 64 + ni * 16 + ccol;
        if (MODE == 5) {
          if (n < 1024) {
            const float v = acc[mi][ni][r] + bias[n];
            ((float*)out0)[(long)m * 1024 + n] = 1.0f / (1.0f + expf(-v));
          } else {
            const float v = acc[mi][ni][r] + bias2[n - 1024];
            ((u16*)out1)[(long)m * 1024 + (n - 1024)] = f2bf(gelu_exact(v));
          }
        } else {
          const float v = acc[mi][ni][r] + bias[n];
          if (MODE == 0) {
            ((u16*)out0)[(long)m * ldo0 + n] = f2bf(gelu_exact(v));
          } else if (MODE == 1) {
            ((float*)out1)[(long)m * 1024 + n] = v;
            ((u16*)out0)[(long)m * ldo0 + n] = f2bf(v);
          } else if (MODE == 2) {
            ((u16*)out0)[(long)m * ldo0 + n] = f2bf(v);
          } else {  // MODE 4
            const float g = gate[(long)m * 1024 + n];
            const float xr = xring[(long)m * 1024 + n];
            ((float*)out0)[(long)m * ldo0 + n] = g * v + (1.0f - g) * xr;
          }
        }
      }
    }
  }
}

// fp32 -> bf16 cast, 4 elems/thread
__global__ __launch_bounds__(256) void cast_bf16(const float* __restrict__ in,
                                                 u16* __restrict__ out, int n4) {
  const long i = (long)blockIdx.x * 256 + threadIdx.x;
  if (i < n4) {
    const float4 v = ((const float4*)in)[i];
    ushort4 o;
    o.x = f2bf(v.x); o.y = f2bf(v.y); o.z = f2bf(v.z); o.w = f2bf(v.w);
    ((ushort4*)out)[i] = o;
  }
}

// W[K,N] fp32 -> Wt[N,K] bf16, 32x32 LDS tile transpose. K = OUT row length.
__global__ __launch_bounds__(256) void transp_bf16(const float* __restrict__ in,
                                                   u16* __restrict__ out, int K,
                                                   int N) {
  __shared__ float tile[32][33];
  const int tx = threadIdx.x & 31;
  const int ty = threadIdx.x >> 5;  // 0..7
  const long r0 = (long)blockIdx.y * 32;
  const long c0 = (long)blockIdx.x * 32;
#pragma unroll
  for (int r = 0; r < 4; r++)
    tile[ty + r * 8][tx] = in[(r0 + ty + r * 8) * N + c0 + tx];
  __syncthreads();
#pragma unroll
  for (int r = 0; r < 4; r++)
    out[(c0 + ty + r * 8) * K + r0 + tx] = f2bf(tile[tx][ty + r * 8]);
}

// S[k,d] = sum_e tc_w2[d,e] * centers[k,e]   (tc2 folded into the logits)
// bc[k]  = sum_e tc_b2[e]   * centers[k,e]
__global__ __launch_bounds__(256) void fold_S(const float* __restrict__ tc_w2,
                                              const float* __restrict__ tc_b2,
                                              const float* __restrict__ centers,
                                              float* __restrict__ S,
                                              float* __restrict__ bc) {
  const int wave = threadIdx.x >> 6, lane = threadIdx.x & 63;
  if (blockIdx.x < 256) {
    const int d = blockIdx.x * 4 + wave;
    const float* row = tc_w2 + (long)d * 1024;
    float s0 = 0.f, s1 = 0.f, s2 = 0.f, s3 = 0.f;
    for (int e = lane; e < 1024; e += 64) {
      const float w = row[e];
      s0 += w * centers[e];
      s1 += w * centers[1024 + e];
      s2 += w * centers[2048 + e];
      s3 += w * centers[3072 + e];
    }
#pragma unroll
    for (int off = 32; off > 0; off >>= 1) {
      s0 += __shfl_xor(s0, off);
      s1 += __shfl_xor(s1, off);
      s2 += __shfl_xor(s2, off);
      s3 += __shfl_xor(s3, off);
    }
    if (lane == 0) {
      S[d] = s0; S[1024 + d] = s1; S[2048 + d] = s2; S[3072 + d] = s3;
    }
  } else {
    const int k = wave;
    float s = 0.f;
    for (int e = lane; e < 1024; e += 64) s += tc_b2[e] * centers[k * 1024 + e];
#pragma unroll
    for (int off = 32; off > 0; off >>= 1) s += __shfl_xor(s, off);
    if (lane == 0) bc[k] = s;
  }
}

// K=4 cluster from h2 directly: logits = h2 . S_k + bc_k, softmax,
// weighted = w @ centers.  One wave per token; bf16 into fus2[:, 1024:2048].
__global__ __launch_bounds__(256) void centers_kernel(
    const u16* __restrict__ h2, const float* __restrict__ S,
    const float* __restrict__ bc, const float* __restrict__ centers,
    u16* __restrict__ fus2) {
  const int lane = threadIdx.x & 63;
  const int wave = threadIdx.x >> 6;
  const long t = (long)blockIdx.x * 4 + wave;
  const u16* row = h2 + t * 1024;
  float d0 = 0.f, d1 = 0.f, d2 = 0.f, d3 = 0.f;
#pragma unroll
  for (int j = 0; j < 2; j++) {
    const int dbase = j * 512 + lane * 8;
    const short8 v = *(const short8*)(row + dbase);
#pragma unroll
    for (int e = 0; e < 8; e++) {
      const float x = bf2f((u16)v[e]);
      const int d = dbase + e;
      d0 += x * S[d];
      d1 += x * S[1024 + d];
      d2 += x * S[2048 + d];
      d3 += x * S[3072 + d];
    }
  }
#pragma unroll
  for (int off = 32; off > 0; off >>= 1) {
    d0 += __shfl_xor(d0, off);
    d1 += __shfl_xor(d1, off);
    d2 += __shfl_xor(d2, off);
    d3 += __shfl_xor(d3, off);
  }
  d0 += bc[0]; d1 += bc[1]; d2 += bc[2]; d3 += bc[3];
  const float mx = fmaxf(fmaxf(d0, d1), fmaxf(d2, d3));
  float e0 = expf(d0 - mx), e1 = expf(d1 - mx), e2 = expf(d2 - mx),
        e3 = expf(d3 - mx);
  const float inv = 1.0f / (e0 + e1 + e2 + e3);
  e0 *= inv; e1 *= inv; e2 *= inv; e3 *= inv;
#pragma unroll
  for (int j = 0; j < 2; j++) {
    const int dbase = j * 512 + lane * 8;
    short8 o;
#pragma unroll
    for (int e = 0; e < 8; e++) {
      const int d = dbase + e;
      const float wv = e0 * centers[d] + e1 * centers[1024 + d] +
                       e2 * centers[2048 + d] + e3 * centers[3072 + d];
      o[e] = (short)f2bf(wv);
    }
    *(short8*)(fus2 + t * 2048 + 1024 + dbase) = o;
  }
}

extern "C" void kernel_launch(void* const* d_in, const int* in_sizes, int n_in,
                              void* d_out, int out_size, void* d_ws,
                              size_t ws_size, hipStream_t stream) {
  const float* queries = (const float*)d_in[0];
  const float* fr_w1 = (const float*)d_in[1];
  const float* fr_b1 = (const float*)d_in[2];
  const float* fr_w2 = (const float*)d_in[3];
  const float* fr_b2 = (const float*)d_in[4];
  const float* tc_w1 = (const float*)d_in[5];
  const float* tc_b1 = (const float*)d_in[6];
  const float* tc_w2 = (const float*)d_in[7];
  const float* tc_b2 = (const float*)d_in[8];
  const float* centers = (const float*)d_in[9];
  const float* fc_w1 = (const float*)d_in[10];
  const float* fc_b1 = (const float*)d_in[11];
  const float* fc_w2 = (const float*)d_in[12];
  const float* fc_b2 = (const float*)d_in[13];
  const float* g_w = (const float*)d_in[14];
  const float* g_b = (const float*)d_in[15];

  char* ws = (char*)d_ws;
  u16* Wt1 = (u16*)ws; ws += (size_t)7168 * 1024 * 2;   // fr_w1^T
  u16* Wt2 = (u16*)ws; ws += (size_t)1024 * 1024 * 2;   // fr_w2^T
  u16* Wt3 = (u16*)ws; ws += (size_t)1024 * 1024 * 2;   // tc_w1^T
  u16* Wt6 = (u16*)ws; ws += (size_t)1024 * 1024 * 2;   // fc_w2^T
  u16* WtG = (u16*)ws; ws += (size_t)2048 * 2048 * 2;   // [g_w^T ; fc_w1^T]
  u16* Xb = (u16*)ws;  ws += (size_t)16384 * 1024 * 2;  // bf16 queries; reused h2, fch
  u16* h1 = (u16*)ws;  ws += (size_t)16384 * 1024 * 2;  // ring hidden
  float* xring = (float*)ws; ws += (size_t)16384 * 1024 * 4;  // x_ring fp32
  u16* fus2 = (u16*)ws; ws += (size_t)16384 * 2048 * 2; // [x_ring_bf16 | weighted]
  float* S = (float*)ws; ws += (size_t)4 * 1024 * 4;    // folded tc_w2@centers^T
  float* bc = (float*)ws; ws += 4 * 4;
  float* gate = (float*)d_out;  // gate f32 lives in d_out (read-then-overwrite)
  float* out = (float*)d_out;

  // --- precision conversions / folds (inputs restored by harness each call) ---
  cast_bf16<<<16384, 256, 0, stream>>>(queries, Xb, 16384 * 1024 / 4);
  transp_bf16<<<dim3(32, 224), 256, 0, stream>>>(fr_w1, Wt1, 7168, 1024);
  transp_bf16<<<dim3(32, 32), 256, 0, stream>>>(fr_w2, Wt2, 1024, 1024);
  transp_bf16<<<dim3(32, 32), 256, 0, stream>>>(tc_w1, Wt3, 1024, 1024);
  transp_bf16<<<dim3(32, 32), 256, 0, stream>>>(fc_w2, Wt6, 1024, 1024);
  transp_bf16<<<dim3(32, 64), 256, 0, stream>>>(g_w, WtG, 2048, 1024);
  transp_bf16<<<dim3(32, 64), 256, 0, stream>>>(fc_w1, WtG + (size_t)1024 * 2048,
                                                2048, 1024);
  fold_S<<<260, 256, 0, stream>>>(tc_w2, tc_b2, centers, S, bc);

  const dim3 grid(8, 128);  // Nout/128 x M/128
  // fr1: gelu(fusion @ fr_w1 + b1) with fused roll-gather -> h1
  gemm128<0, true><<<grid, 256, 0, stream>>>(Xb, 0, Wt1, 7168, fr_b1, nullptr,
                                             h1, 1024, nullptr, nullptr, nullptr);
  // fr2: x_ring = h1 @ fr_w2 + b2 -> xring(f32) + fus2[:, :1024](bf16)
  gemm128<1, false><<<grid, 256, 0, stream>>>(h1, 1024, Wt2, 1024, fr_b2,
                                              nullptr, fus2, 2048, xring,
                                              nullptr, nullptr);
  // tc1: h2 = gelu(x_ring @ tc_w1 + b1) -> Xb
  gemm128<0, false><<<grid, 256, 0, stream>>>(fus2, 2048, Wt3, 1024, tc_b1,
                                              nullptr, Xb, 1024, nullptr,
                                              nullptr, nullptr);
  // folded tc2 + softmax over 4 centers + weighted sum -> fus2[:, 1024:2048]
  centers_kernel<<<4096, 256, 0, stream>>>(Xb, S, bc, centers, fus2);
  // merged: gate = sigmoid(fus2@g_w+g_b) -> d_out ; fch = gelu(fus2@fc_w1+b1) -> Xb
  gemm128<5, false><<<dim3(16, 128), 256, 0, stream>>>(
      fus2, 2048, WtG, 2048, g_b, fc_b1, gate, 1024, Xb, nullptr, nullptr);
  // fc2 + final mix: out = gate*(fch @ fc_w2 + b2) + (1-gate)*x_ring
  gemm128<4, false><<<grid, 256, 0, stream>>>(Xb, 1024, Wt6, 1024, fc_b2,
                                              nullptr, out, 1024, nullptr,
                                              gate, xring);
}